// Round 3
// baseline (986.350 us; speedup 1.0000x reference)
//
#include <hip/hip_runtime.h>
#include <hip/hip_bf16.h>

// ---------------------------------------------------------------------------
// DGLRGCN on MI355X: CSR-bucketed gather (no atomics) + fused bf16 MFMA GEMMs
// (K = 6*256). Round 3: 64x64 GEMM tiles for occupancy, adaptive bf16-x
// gather path (L3-resident), single weight-convert launch.
// ---------------------------------------------------------------------------

#define HD   256
#define EPS  1e-5f
#define NREL 5
#define ND0  50000
#define ND1  10000
#define BK   64
#define PAD  8      // LDS row pad (ushorts): stride 72 us = 144 B (16B-aligned)

typedef unsigned short ushort_t;
using f32x4  = __attribute__((ext_vector_type(4))) float;
using short8 = __attribute__((ext_vector_type(8))) short;

__device__ __forceinline__ ushort_t f2b(float f) {
    union { float f; unsigned u; } x; x.f = f;
    unsigned r = x.u + 0x7FFF + ((x.u >> 16) & 1);   // RNE
    return (ushort_t)(r >> 16);
}
__device__ __forceinline__ float b2f(ushort_t h) {
    union { unsigned u; float f; } x; x.u = ((unsigned)h) << 16;
    return x.f;
}

// ---------------- all weights: src[K=256][N] fp32 -> dst[256][256] bf16 -----
struct WconvArgs {
    const float* src[14];
    ushort_t*    dst[14];
    int          N[14];
};
__global__ void wconv_all_kernel(WconvArgs a) {
    int mat = blockIdx.x >> 8;
    int id = (blockIdx.x & 255) * 256 + threadIdx.x;   // 0..65535
    int n = id >> 8, k = id & 255;
    int N = a.N[mat];
    float v = (n < N) ? a.src[mat][(size_t)k * N + n] : 0.f;
    a.dst[mat][id] = f2b(v);
}

// ---------------- x fp32 -> bf16 -------------------------------------------
__global__ void xconv_kernel(const float* __restrict__ x, ushort_t* __restrict__ xb,
                             int n64) {
    int id = blockIdx.x * 256 + threadIdx.x;
    if (id >= n64) return;
    float4 v = ((const float4*)x)[id];
    ushort4 o; o.x = f2b(v.x); o.y = f2b(v.y); o.z = f2b(v.z); o.w = f2b(v.w);
    ((ushort4*)xb)[id] = o;
}

// ---------------- CSR build ------------------------------------------------
__global__ void count_kernel(const int* __restrict__ dst, const int* __restrict__ et,
                             int E, int ND, int* __restrict__ cnt, int* __restrict__ pos) {
    int e = blockIdx.x * 256 + threadIdx.x;
    if (e >= E) return;
    pos[e] = atomicAdd(&cnt[et[e] * ND + dst[e]], 1);
}

__global__ void scan_block_kernel(const int* __restrict__ in, int* __restrict__ out,
                                  int* __restrict__ bsum, int nb) {
    __shared__ int ts[256];
    int tid = threadIdx.x;
    int base = blockIdx.x * 1024 + tid * 4;
    int v0 = (base + 0 < nb) ? in[base + 0] : 0;
    int v1 = (base + 1 < nb) ? in[base + 1] : 0;
    int v2 = (base + 2 < nb) ? in[base + 2] : 0;
    int v3 = (base + 3 < nb) ? in[base + 3] : 0;
    int tsum = v0 + v1 + v2 + v3;
    ts[tid] = tsum;
    __syncthreads();
    for (int d = 1; d < 256; d <<= 1) {
        int t = (tid >= d) ? ts[tid - d] : 0;
        __syncthreads();
        ts[tid] += t;
        __syncthreads();
    }
    int excl = ts[tid] - tsum;
    if (base + 0 < nb) out[base + 0] = excl;
    if (base + 1 < nb) out[base + 1] = excl + v0;
    if (base + 2 < nb) out[base + 2] = excl + v0 + v1;
    if (base + 3 < nb) out[base + 3] = excl + v0 + v1 + v2;
    if (tid == 255 && bsum) bsum[blockIdx.x] = ts[255];
}

__global__ void scan_add_kernel(int* __restrict__ out, const int* __restrict__ bsum, int nb) {
    int i = blockIdx.x * 256 + threadIdx.x;
    if (i < nb) out[i] += bsum[i >> 10];
}

__global__ void fill_kernel(const int* __restrict__ src, const int* __restrict__ dst,
                            const int* __restrict__ et, const int* __restrict__ pos,
                            const int* __restrict__ off, int E, int ND,
                            int* __restrict__ ssrc) {
    int e = blockIdx.x * 256 + threadIdx.x;
    if (e >= E) return;
    ssrc[off[et[e] * ND + dst[e]] + pos[e]] = src[e];
}

// ---------------- gather-sum, one wave per (r,dst) bucket ------------------
__global__ void gather_f32_kernel(const float* __restrict__ feat, const int* __restrict__ ssrc,
                                  const int* __restrict__ cnt, const int* __restrict__ off,
                                  int ND, int c0, int rows, ushort_t* __restrict__ out) {
    int wave = (blockIdx.x * 256 + threadIdx.x) >> 6;
    int lane = threadIdx.x & 63;
    if (wave >= NREL * rows) return;
    int r = wave / rows, i = wave - r * rows;
    int b = r * ND + c0 + i;
    int deg = cnt[b], s = off[b];
    float a0 = 0, a1 = 0, a2 = 0, a3 = 0;
    int j = 0;
    for (; j + 2 <= deg; j += 2) {
        int r0 = ssrc[s + j], r1 = ssrc[s + j + 1];
        float4 v0 = ((const float4*)(feat + (size_t)r0 * HD))[lane];
        float4 v1 = ((const float4*)(feat + (size_t)r1 * HD))[lane];
        a0 += v0.x + v1.x; a1 += v0.y + v1.y;
        a2 += v0.z + v1.z; a3 += v0.w + v1.w;
    }
    if (j < deg) {
        float4 v = ((const float4*)(feat + (size_t)ssrc[s + j] * HD))[lane];
        a0 += v.x; a1 += v.y; a2 += v.z; a3 += v.w;
    }
    ushort4 o; o.x = f2b(a0); o.y = f2b(a1); o.z = f2b(a2); o.w = f2b(a3);
    ((ushort4*)(out + (size_t)wave * HD))[lane] = o;
}

__global__ void gather_b16_kernel(const ushort_t* __restrict__ feat, const int* __restrict__ ssrc,
                                  const int* __restrict__ cnt, const int* __restrict__ off,
                                  int ND, int c0, int rows, ushort_t* __restrict__ out) {
    int wave = (blockIdx.x * 256 + threadIdx.x) >> 6;
    int lane = threadIdx.x & 63;
    if (wave >= NREL * rows) return;
    int r = wave / rows, i = wave - r * rows;
    int b = r * ND + c0 + i;
    int deg = cnt[b], s = off[b];
    float a0 = 0, a1 = 0, a2 = 0, a3 = 0;
    int j = 0;
    for (; j + 2 <= deg; j += 2) {
        int r0 = ssrc[s + j], r1 = ssrc[s + j + 1];
        ushort4 v0 = ((const ushort4*)(feat + (size_t)r0 * HD))[lane];
        ushort4 v1 = ((const ushort4*)(feat + (size_t)r1 * HD))[lane];
        a0 += b2f(v0.x) + b2f(v1.x); a1 += b2f(v0.y) + b2f(v1.y);
        a2 += b2f(v0.z) + b2f(v1.z); a3 += b2f(v0.w) + b2f(v1.w);
    }
    if (j < deg) {
        ushort4 v = ((const ushort4*)(feat + (size_t)ssrc[s + j] * HD))[lane];
        a0 += b2f(v.x); a1 += b2f(v.y); a2 += b2f(v.z); a3 += b2f(v.w);
    }
    ushort4 o; o.x = f2b(a0); o.y = f2b(a1); o.z = f2b(a2); o.w = f2b(a3);
    ((ushort4*)(out + (size_t)wave * HD))[lane] = o;
}

// ---------------- fused MFMA GEMM: C = [A_0|..|A_{n-1}] @ [B_0;..] + bias ---
// 64x64 tile, 4 waves (2x2), wave 32x32 via 2x2 mfma_f32_16x16x32_bf16.
// A reads past M are unguarded (land in ws pad, masked at store).
struct GemmArgs {
    const void*     A[6];
    const ushort_t* B[6];
    int             a_f32[6];
    int             nseg;
    const float*    bias;
    ushort_t*       Cb;      // bf16 out, stride 256 (or null)
    float*          Cf;      // fp32 out, stride N  (or null)
    int             M, N;
};

__launch_bounds__(256)
__global__ void gemm_mfma_kernel(GemmArgs g) {
    __shared__ __align__(16) ushort_t As[64][BK + PAD];
    __shared__ __align__(16) ushort_t Bs[64][BK + PAD];
    int tid = threadIdx.x;
    int wave = tid >> 6, lane = tid & 63;
    int wm = (wave >> 1) * 32, wn = (wave & 1) * 32;
    int bm = blockIdx.y * 64, bn = blockIdx.x * 64;
    f32x4 acc[2][2] = {};
    int K = g.nseg * HD;

    for (int kk = 0; kk < K; kk += BK) {
        int s = kk >> 8;
        int kl = kk & 255;
        if (g.a_f32[s]) {
            const float* Ap = (const float*)g.A[s];
#pragma unroll
            for (int it = 0; it < 4; it++) {
                int idx = tid + it * 256;          // 0..1023
                int row = idx >> 4, c4 = idx & 15;
                float4 v = ((const float4*)(Ap + (size_t)(bm + row) * HD + kl))[c4];
                uint2 p;
                p.x = (unsigned)f2b(v.x) | ((unsigned)f2b(v.y) << 16);
                p.y = (unsigned)f2b(v.z) | ((unsigned)f2b(v.w) << 16);
                *(uint2*)&As[row][c4 * 4] = p;
            }
        } else {
            const ushort_t* Ap = (const ushort_t*)g.A[s];
#pragma unroll
            for (int it = 0; it < 2; it++) {
                int idx = tid + it * 256;          // 0..511
                int row = idx >> 3, c8 = idx & 7;
                *(uint4*)&As[row][c8 * 8] =
                    *(const uint4*)(Ap + (size_t)(bm + row) * HD + kl + c8 * 8);
            }
        }
        {
            const ushort_t* Bp = g.B[s];
#pragma unroll
            for (int it = 0; it < 2; it++) {
                int idx = tid + it * 256;
                int row = idx >> 3, c8 = idx & 7;
                *(uint4*)&Bs[row][c8 * 8] =
                    *(const uint4*)(Bp + (size_t)(bn + row) * HD + kl + c8 * 8);
            }
        }
        __syncthreads();
#pragma unroll
        for (int ks = 0; ks < BK; ks += 32) {
            int kq = ks + (lane >> 4) * 8;
            short8 a[2], b[2];
#pragma unroll
            for (int mi = 0; mi < 2; mi++)
                a[mi] = *(const short8*)&As[wm + mi * 16 + (lane & 15)][kq];
#pragma unroll
            for (int ni = 0; ni < 2; ni++)
                b[ni] = *(const short8*)&Bs[wn + ni * 16 + (lane & 15)][kq];
#pragma unroll
            for (int mi = 0; mi < 2; mi++)
#pragma unroll
                for (int ni = 0; ni < 2; ni++)
                    acc[mi][ni] = __builtin_amdgcn_mfma_f32_16x16x32_bf16(
                        a[mi], b[ni], acc[mi][ni], 0, 0, 0);
        }
        __syncthreads();
    }

    int rq = lane >> 4, ci = lane & 15;
#pragma unroll
    for (int mi = 0; mi < 2; mi++)
#pragma unroll
        for (int ni = 0; ni < 2; ni++)
#pragma unroll
            for (int reg = 0; reg < 4; reg++) {
                int row = bm + wm + mi * 16 + rq * 4 + reg;
                int col = bn + wn + ni * 16 + ci;
                if (row < g.M && col < g.N) {
                    float v = acc[mi][ni][reg];
                    if (g.bias) v += g.bias[col];
                    if (g.Cb) g.Cb[(size_t)row * HD + col] = f2b(v);
                    else      g.Cf[(size_t)row * g.N + col] = v;
                }
            }
}

// ---------------- BN ------------------------------------------------------
__global__ void bn_stats_kernel(const ushort_t* __restrict__ Hb, int M,
                                float* __restrict__ sums) {
    int col = threadIdx.x;
    float s = 0.f, s2 = 0.f;
    for (int i = blockIdx.x; i < M; i += gridDim.x) {
        float v = b2f(Hb[(size_t)i * HD + col]);
        s += v; s2 += v * v;
    }
    atomicAdd(&sums[col], s);
    atomicAdd(&sums[HD + col], s2);
}

__global__ void bn_apply_kernel(ushort_t* __restrict__ Hb, int M,
                                const float* __restrict__ sums,
                                const float* __restrict__ g,
                                const float* __restrict__ be, int relu) {
    int id = blockIdx.x * 256 + threadIdx.x;
    if (id >= M * 64) return;
    int row = id >> 6, l = id & 63;
    ushort4* p = (ushort4*)(Hb + (size_t)row * HD) + l;
    ushort4 v4 = *p;
    float vv[4] = {b2f(v4.x), b2f(v4.y), b2f(v4.z), b2f(v4.w)};
    float invM = 1.f / (float)M;
    int c = l * 4;
    ushort4 o;
    ushort_t* op = (ushort_t*)&o;
#pragma unroll
    for (int j = 0; j < 4; j++) {
        float mu = sums[c + j] * invM;
        float var = sums[HD + c + j] * invM - mu * mu;
        float t = g[c + j] * (vv[j] - mu) * rsqrtf(var + EPS) + be[c + j];
        t = relu ? fmaxf(t, 0.f) : (t > 0.f ? t : expm1f(t));
        op[j] = f2b(t);
    }
    *p = o;
}

// ---------------------------------------------------------------------------
extern "C" void kernel_launch(void* const* d_in, const int* in_sizes, int n_in,
                              void* d_out, int out_size, void* d_ws, size_t ws_size,
                              hipStream_t stream) {
    const float* x   = (const float*)d_in[0];
    const int* src0  = (const int*)d_in[1];
    const int* dst0  = (const int*)d_in[2];
    const int* et0   = (const int*)d_in[3];
    const int* src1  = (const int*)d_in[4];
    const int* dst1  = (const int*)d_in[5];
    const int* et1   = (const int*)d_in[6];
    const float* W0  = (const float*)d_in[9];
    const float* Wl0 = (const float*)d_in[10];
    const float* b0  = (const float*)d_in[11];
    const float* g0  = (const float*)d_in[12];
    const float* be0 = (const float*)d_in[13];
    const float* W1  = (const float*)d_in[14];
    const float* Wl1 = (const float*)d_in[15];
    const float* b1  = (const float*)d_in[16];
    const float* g1  = (const float*)d_in[17];
    const float* be1 = (const float*)d_in[18];
    const float* Wm1 = (const float*)d_in[19];
    const float* bm1 = (const float*)d_in[20];
    const float* gm  = (const float*)d_in[21];
    const float* bem = (const float*)d_in[22];
    const float* Wm2 = (const float*)d_in[23];
    const float* bm2 = (const float*)d_in[24];

    const int E0 = in_sizes[1];
    const int E1 = in_sizes[4];
    const int NOUT = in_sizes[24];   // 153
    const int NSRC = in_sizes[0] / HD;  // 200000

    // ---------------- ws layout -------------------------------------------
    ushort_t* Wt  = (ushort_t*)d_ws;             // 14 x 65536 bf16
    float* st  = (float*)(Wt + 14 * 65536);      // 4096 reserved
    int* cnt   = (int*)(st + 4096);              // 250000
    int* off   = cnt + 250000;                   // 250000
    int* bsum  = off + 250000;                   // 1024
    int* pos   = bsum + 1024;                    // 800000
    int* ssrc  = pos + 800000;                   // 800000
    ushort_t* h0b = (ushort_t*)(ssrc + 800000);  // 50000*256
    ushort_t* h1b = h0b + (size_t)ND0 * HD;      // 10000*256
    ushort_t* mb  = h1b + (size_t)ND1 * HD;      // 10000*256
    ushort_t* tail = mb + (size_t)ND1 * HD;

    // FULL path: bf16 x copy (L3-resident) + 4 gather chunks. Needs ~180.6 MB.
    const bool full = ws_size >= (size_t)181000000;
    const int nchunk = full ? 4 : 2;
    const int crows  = full ? 12500 : 25000;
    ushort_t* xb = full ? tail : nullptr;
    ushort_t* S  = full ? (xb + (size_t)NSRC * HD) : tail;

    ushort_t* W0t  = Wt;
    ushort_t* Wl0t = Wt + 5 * 65536;
    ushort_t* W1t  = Wt + 6 * 65536;
    ushort_t* Wl1t = Wt + 11 * 65536;
    ushort_t* Wm1t = Wt + 12 * 65536;
    ushort_t* Wm2t = Wt + 13 * 65536;

    // ---------------- weights -> bf16 transposed (one launch) --------------
    {
        WconvArgs wa;
        for (int r = 0; r < NREL; r++) { wa.src[r] = W0 + (size_t)r * 65536; wa.dst[r] = W0t + (size_t)r * 65536; wa.N[r] = 256; }
        wa.src[5] = Wl0; wa.dst[5] = Wl0t; wa.N[5] = 256;
        for (int r = 0; r < NREL; r++) { wa.src[6 + r] = W1 + (size_t)r * 65536; wa.dst[6 + r] = W1t + (size_t)r * 65536; wa.N[6 + r] = 256; }
        wa.src[11] = Wl1; wa.dst[11] = Wl1t; wa.N[11] = 256;
        wa.src[12] = Wm1; wa.dst[12] = Wm1t; wa.N[12] = 256;
        wa.src[13] = Wm2; wa.dst[13] = Wm2t; wa.N[13] = NOUT;
        wconv_all_kernel<<<14 * 256, 256, 0, stream>>>(wa);
    }
    if (full)
        xconv_kernel<<<(NSRC * 64 + 255) / 256, 256, 0, stream>>>(x, xb, NSRC * 64);

    hipMemsetAsync(st, 0, 1536 * sizeof(float), stream);

    // ---------------- layer 0 CSR ------------------------------------------
    hipMemsetAsync(cnt, 0, NREL * ND0 * sizeof(int), stream);
    count_kernel<<<(E0 + 255) / 256, 256, 0, stream>>>(dst0, et0, E0, ND0, cnt, pos);
    scan_block_kernel<<<(NREL * ND0 + 1023) / 1024, 256, 0, stream>>>(cnt, off, bsum, NREL * ND0);
    scan_block_kernel<<<1, 256, 0, stream>>>(bsum, bsum, nullptr, (NREL * ND0 + 1023) / 1024);
    scan_add_kernel<<<(NREL * ND0 + 255) / 256, 256, 0, stream>>>(off, bsum, NREL * ND0);
    fill_kernel<<<(E0 + 255) / 256, 256, 0, stream>>>(src0, dst0, et0, pos, off, E0, ND0, ssrc);

    // ---------------- layer 0 chunks: gather + fused GEMM ------------------
    for (int c = 0; c < nchunk; c++) {
        int c0 = c * crows;
        int gblocks = (NREL * crows * 64) / 256;
        if (full)
            gather_b16_kernel<<<gblocks, 256, 0, stream>>>(xb, ssrc, cnt, off, ND0, c0, crows, S);
        else
            gather_f32_kernel<<<gblocks, 256, 0, stream>>>(x, ssrc, cnt, off, ND0, c0, crows, S);
        GemmArgs ga = {};
        for (int s = 0; s < NREL; s++) {
            ga.A[s] = S + (size_t)s * crows * HD;
            ga.B[s] = W0t + (size_t)s * 65536;
            ga.a_f32[s] = 0;
        }
        if (full) { ga.A[5] = xb + (size_t)c0 * HD; ga.a_f32[5] = 0; }
        else      { ga.A[5] = x + (size_t)c0 * HD;  ga.a_f32[5] = 1; }
        ga.B[5] = Wl0t;
        ga.nseg = 6; ga.bias = b0;
        ga.Cb = h0b + (size_t)c0 * HD; ga.Cf = nullptr;
        ga.M = crows; ga.N = HD;
        gemm_mfma_kernel<<<dim3(HD / 64, (crows + 63) / 64), 256, 0, stream>>>(ga);
    }
    bn_stats_kernel<<<256, 256, 0, stream>>>(h0b, ND0, st);
    bn_apply_kernel<<<(ND0 * 64) / 256, 256, 0, stream>>>(h0b, ND0, st, g0, be0, 0);

    // ---------------- layer 1 ----------------------------------------------
    hipMemsetAsync(cnt, 0, NREL * ND1 * sizeof(int), stream);
    count_kernel<<<(E1 + 255) / 256, 256, 0, stream>>>(dst1, et1, E1, ND1, cnt, pos);
    scan_block_kernel<<<(NREL * ND1 + 1023) / 1024, 256, 0, stream>>>(cnt, off, bsum, NREL * ND1);
    scan_block_kernel<<<1, 256, 0, stream>>>(bsum, bsum, nullptr, (NREL * ND1 + 1023) / 1024);
    scan_add_kernel<<<(NREL * ND1 + 255) / 256, 256, 0, stream>>>(off, bsum, NREL * ND1);
    fill_kernel<<<(E1 + 255) / 256, 256, 0, stream>>>(src1, dst1, et1, pos, off, E1, ND1, ssrc);

    gather_b16_kernel<<<(NREL * ND1 * 64) / 256, 256, 0, stream>>>(h0b, ssrc, cnt, off, ND1, 0, ND1, S);
    {
        GemmArgs ga = {};
        for (int s = 0; s < NREL; s++) {
            ga.A[s] = S + (size_t)s * ND1 * HD;
            ga.B[s] = W1t + (size_t)s * 65536;
            ga.a_f32[s] = 0;
        }
        ga.A[5] = h0b; ga.a_f32[5] = 0; ga.B[5] = Wl1t;
        ga.nseg = 6; ga.bias = b1;
        ga.Cb = h1b; ga.Cf = nullptr; ga.M = ND1; ga.N = HD;
        gemm_mfma_kernel<<<dim3(HD / 64, (ND1 + 63) / 64), 256, 0, stream>>>(ga);
    }
    bn_stats_kernel<<<256, 256, 0, stream>>>(h1b, ND1, st + 512);
    bn_apply_kernel<<<(ND1 * 64) / 256, 256, 0, stream>>>(h1b, ND1, st + 512, g1, be1, 0);

    // ---------------- MLP head ---------------------------------------------
    {
        GemmArgs ga = {};
        ga.A[0] = h1b; ga.a_f32[0] = 0; ga.B[0] = Wm1t;
        ga.nseg = 1; ga.bias = bm1;
        ga.Cb = mb; ga.Cf = nullptr; ga.M = ND1; ga.N = HD;
        gemm_mfma_kernel<<<dim3(HD / 64, (ND1 + 63) / 64), 256, 0, stream>>>(ga);
    }
    bn_stats_kernel<<<256, 256, 0, stream>>>(mb, ND1, st + 1024);
    bn_apply_kernel<<<(ND1 * 64) / 256, 256, 0, stream>>>(mb, ND1, st + 1024, gm, bem, 1);
    {
        GemmArgs ga = {};
        ga.A[0] = mb; ga.a_f32[0] = 0; ga.B[0] = Wm2t;
        ga.nseg = 1; ga.bias = bm2;
        ga.Cb = nullptr; ga.Cf = (float*)d_out; ga.M = ND1; ga.N = NOUT;
        gemm_mfma_kernel<<<dim3((NOUT + 63) / 64, (ND1 + 63) / 64), 256, 0, stream>>>(ga);
    }
}

// Round 4
// 820.704 us; speedup vs baseline: 1.2018x; 1.2018x over previous
//
#include <hip/hip_runtime.h>
#include <hip/hip_bf16.h>

// ---------------------------------------------------------------------------
// DGLRGCN on MI355X. Round 4: single gather + single fused GEMM per layer
// (ws is ~819 MB, no chunking), merged 2-layer CSR build, BN stats fused into
// GEMM epilogues, BN+activation fused into consumer A-loads / gather.
// ---------------------------------------------------------------------------

#define HD   256
#define EPS  1e-5f
#define NREL 5
#define ND0  50000
#define ND1  10000
#define BK   64
#define PAD  8      // LDS row pad (ushorts): stride 72 us = 144 B

typedef unsigned short ushort_t;
using f32x4  = __attribute__((ext_vector_type(4))) float;
using short8 = __attribute__((ext_vector_type(8))) short;

__device__ __forceinline__ ushort_t f2b(float f) {
    union { float f; unsigned u; } x; x.f = f;
    unsigned r = x.u + 0x7FFF + ((x.u >> 16) & 1);   // RNE
    return (ushort_t)(r >> 16);
}
__device__ __forceinline__ float b2f(ushort_t h) {
    union { unsigned u; float f; } x; x.u = ((unsigned)h) << 16;
    return x.f;
}

// ---------------- all weights: src[K=256][N] fp32 -> dst[256][256] bf16 -----
struct WconvArgs {
    const float* src[14];
    ushort_t*    dst[14];
    int          N[14];
};
__global__ void wconv_all_kernel(WconvArgs a) {
    int mat = blockIdx.x >> 8;
    int id = (blockIdx.x & 255) * 256 + threadIdx.x;   // 0..65535
    int n = id >> 8, k = id & 255;
    int N = a.N[mat];
    float v = (n < N) ? a.src[mat][(size_t)k * N + n] : 0.f;
    a.dst[mat][id] = f2b(v);
}

// ---------------- x fp32 -> bf16 -------------------------------------------
__global__ void xconv_kernel(const float* __restrict__ x, ushort_t* __restrict__ xb,
                             int n4) {
    int id = blockIdx.x * 256 + threadIdx.x;
    if (id >= n4) return;
    float4 v = ((const float4*)x)[id];
    ushort4 o; o.x = f2b(v.x); o.y = f2b(v.y); o.z = f2b(v.z); o.w = f2b(v.w);
    ((ushort4*)xb)[id] = o;
}

// ---------------- combined CSR build (both layers) -------------------------
// bucket id: layer0 -> et*ND0 + dst;  layer1 -> 250000 + et*ND1 + dst
__global__ void count2_kernel(const int* __restrict__ d0, const int* __restrict__ e0, int E0,
                              const int* __restrict__ d1, const int* __restrict__ e1, int E1,
                              int* __restrict__ cnt, int* __restrict__ pos) {
    int e = blockIdx.x * 256 + threadIdx.x;
    if (e < E0) {
        pos[e] = atomicAdd(&cnt[e0[e] * ND0 + d0[e]], 1);
    } else if (e < E0 + E1) {
        int i = e - E0;
        pos[e] = atomicAdd(&cnt[NREL * ND0 + e1[i] * ND1 + d1[i]], 1);
    }
}

__global__ void scan_block_kernel(const int* __restrict__ in, int* __restrict__ out,
                                  int* __restrict__ bsum, int nb) {
    __shared__ int ts[256];
    int tid = threadIdx.x;
    int base = blockIdx.x * 1024 + tid * 4;
    int v0 = (base + 0 < nb) ? in[base + 0] : 0;
    int v1 = (base + 1 < nb) ? in[base + 1] : 0;
    int v2 = (base + 2 < nb) ? in[base + 2] : 0;
    int v3 = (base + 3 < nb) ? in[base + 3] : 0;
    int tsum = v0 + v1 + v2 + v3;
    ts[tid] = tsum;
    __syncthreads();
    for (int d = 1; d < 256; d <<= 1) {
        int t = (tid >= d) ? ts[tid - d] : 0;
        __syncthreads();
        ts[tid] += t;
        __syncthreads();
    }
    int excl = ts[tid] - tsum;
    if (base + 0 < nb) out[base + 0] = excl;
    if (base + 1 < nb) out[base + 1] = excl + v0;
    if (base + 2 < nb) out[base + 2] = excl + v0 + v1;
    if (base + 3 < nb) out[base + 3] = excl + v0 + v1 + v2;
    if (tid == 255 && bsum) bsum[blockIdx.x] = ts[255];
}

__global__ void scan_add_kernel(int* __restrict__ out, const int* __restrict__ bsum, int nb) {
    int i = blockIdx.x * 256 + threadIdx.x;
    if (i < nb) out[i] += bsum[i >> 10];
}

__global__ void fill2_kernel(const int* __restrict__ s0, const int* __restrict__ d0,
                             const int* __restrict__ e0, int E0,
                             const int* __restrict__ s1, const int* __restrict__ d1,
                             const int* __restrict__ e1, int E1,
                             const int* __restrict__ pos, const int* __restrict__ off,
                             int* __restrict__ ssrc) {
    int e = blockIdx.x * 256 + threadIdx.x;
    if (e < E0) {
        ssrc[off[e0[e] * ND0 + d0[e]] + pos[e]] = s0[e];
    } else if (e < E0 + E1) {
        int i = e - E0;
        ssrc[off[NREL * ND0 + e1[i] * ND1 + d1[i]] + pos[e]] = s1[i];
    }
}

// ---------------- gather-sum, one wave per bucket; optional fused BN+ELU ----
__global__ void gather_kernel(const ushort_t* __restrict__ feat, const int* __restrict__ ssrc,
                              const int* __restrict__ cnt, const int* __restrict__ off,
                              int nbuckets, ushort_t* __restrict__ out,
                              const float* __restrict__ sc, const float* __restrict__ sh) {
    int wave = (blockIdx.x * 256 + threadIdx.x) >> 6;
    int lane = threadIdx.x & 63;
    if (wave >= nbuckets) return;
    int deg = cnt[wave], s = off[wave];
    float4 scv = {0, 0, 0, 0}, shv = {0, 0, 0, 0};
    if (sc) { scv = ((const float4*)sc)[lane]; shv = ((const float4*)sh)[lane]; }
    float a0 = 0, a1 = 0, a2 = 0, a3 = 0;
    if (sc) {
        for (int j = 0; j < deg; j++) {
            ushort4 v = ((const ushort4*)(feat + (size_t)ssrc[s + j] * HD))[lane];
            float f0 = fmaf(b2f(v.x), scv.x, shv.x);
            float f1 = fmaf(b2f(v.y), scv.y, shv.y);
            float f2 = fmaf(b2f(v.z), scv.z, shv.z);
            float f3 = fmaf(b2f(v.w), scv.w, shv.w);
            a0 += f0 > 0.f ? f0 : expm1f(f0);
            a1 += f1 > 0.f ? f1 : expm1f(f1);
            a2 += f2 > 0.f ? f2 : expm1f(f2);
            a3 += f3 > 0.f ? f3 : expm1f(f3);
        }
    } else {
        int j = 0;
        for (; j + 2 <= deg; j += 2) {
            int r0 = ssrc[s + j], r1 = ssrc[s + j + 1];
            ushort4 v0 = ((const ushort4*)(feat + (size_t)r0 * HD))[lane];
            ushort4 v1 = ((const ushort4*)(feat + (size_t)r1 * HD))[lane];
            a0 += b2f(v0.x) + b2f(v1.x); a1 += b2f(v0.y) + b2f(v1.y);
            a2 += b2f(v0.z) + b2f(v1.z); a3 += b2f(v0.w) + b2f(v1.w);
        }
        if (j < deg) {
            ushort4 v = ((const ushort4*)(feat + (size_t)ssrc[s + j] * HD))[lane];
            a0 += b2f(v.x); a1 += b2f(v.y); a2 += b2f(v.z); a3 += b2f(v.w);
        }
    }
    ushort4 o; o.x = f2b(a0); o.y = f2b(a1); o.z = f2b(a2); o.w = f2b(a3);
    ((ushort4*)(out + (size_t)wave * HD))[lane] = o;
}

// ---------------- BN param prep: sc[c], sh[c] from sums --------------------
__global__ void bnprep_kernel(const float* __restrict__ sums, const float* __restrict__ g,
                              const float* __restrict__ be, float invM,
                              float* __restrict__ sc, float* __restrict__ sh) {
    int c = threadIdx.x;
    float mu = sums[c] * invM;
    float var = sums[HD + c] * invM - mu * mu;
    float s = g[c] * rsqrtf(var + EPS);
    sc[c] = s; sh[c] = be[c] - mu * s;
}

// ---------------- fused MFMA GEMM ------------------------------------------
// C = sum_s act_s(BN_s(A_s)) @ B_s + bias; optional per-column stats epilogue.
// A_s row-major [M][256] bf16 (rows past M read from pad, discarded at store
// and excluded from stats). B_s bf16 [256 n][256 k]. BM=128: 4 waves 2x2, 4x4
// frags; BM=64: 2x2 frags.
struct Seg {
    const ushort_t* A;
    const ushort_t* B;
    const float* sc;    // null = raw
    const float* sh;
    int act;            // 1=ELU, 2=ReLU
};
struct GemmArgs {
    Seg seg[6];
    int nseg;
    const float* bias;
    float* stats;        // null or [512]: colsum, colsumsq
    ushort_t* Cb;        // bf16 out, stride 256 (or null)
    float* Cf;           // fp32 out, stride N
    int M, N;
};

template <int BM>
__launch_bounds__(256)
__global__ void gemm_mfma_kernel(GemmArgs g) {
    constexpr int F = BM / 32;
    __shared__ __align__(16) ushort_t As[BM][BK + PAD];
    __shared__ __align__(16) ushort_t Bs[BM][BK + PAD];
    int tid = threadIdx.x;
    int wave = tid >> 6, lane = tid & 63;
    int rq = lane >> 4, ci = lane & 15;
    int wm = (wave >> 1) * (BM / 2), wn = (wave & 1) * (BM / 2);
    int bm = blockIdx.y * BM, bn = blockIdx.x * BM;
    f32x4 acc[F][F] = {};
    int K = g.nseg * HD;

    for (int kk = 0; kk < K; kk += BK) {
        int si = kk >> 8;
        int kl = kk & 255;
        const ushort_t* Ap = g.seg[si].A;
        const ushort_t* Bp = g.seg[si].B;
        const float* sc = g.seg[si].sc;
#pragma unroll
        for (int it = 0; it < BM / 32; it++) {
            int idx = tid + it * 256;
            int row = idx >> 3, c8 = idx & 7;
            uint4 v = *(const uint4*)(Ap + (size_t)(bm + row) * HD + kl + c8 * 8);
            if (sc) {
                const float* sh = g.seg[si].sh;
                int act = g.seg[si].act;
                ushort_t* u = (ushort_t*)&v;
                int kb = kl + c8 * 8;
#pragma unroll
                for (int j = 0; j < 8; j++) {
                    float f = fmaf(b2f(u[j]), sc[kb + j], sh[kb + j]);
                    f = (act == 2) ? fmaxf(f, 0.f) : (f > 0.f ? f : expm1f(f));
                    u[j] = f2b(f);
                }
            }
            *(uint4*)&As[row][c8 * 8] = v;
        }
#pragma unroll
        for (int it = 0; it < BM / 32; it++) {
            int idx = tid + it * 256;
            int row = idx >> 3, c8 = idx & 7;
            *(uint4*)&Bs[row][c8 * 8] =
                *(const uint4*)(Bp + (size_t)(bn + row) * HD + kl + c8 * 8);
        }
        __syncthreads();
#pragma unroll
        for (int ks = 0; ks < BK; ks += 32) {
            int kq = ks + rq * 8;
            short8 a[F], b[F];
#pragma unroll
            for (int mi = 0; mi < F; mi++)
                a[mi] = *(const short8*)&As[wm + mi * 16 + ci][kq];
#pragma unroll
            for (int ni = 0; ni < F; ni++)
                b[ni] = *(const short8*)&Bs[wn + ni * 16 + ci][kq];
#pragma unroll
            for (int mi = 0; mi < F; mi++)
#pragma unroll
                for (int ni = 0; ni < F; ni++)
                    acc[mi][ni] = __builtin_amdgcn_mfma_f32_16x16x32_bf16(
                        a[mi], b[ni], acc[mi][ni], 0, 0, 0);
        }
        __syncthreads();
    }

    // bias (before stats, matching reference h = agg + bias)
#pragma unroll
    for (int ni = 0; ni < F; ni++) {
        int col = bn + wn + ni * 16 + ci;
        float bv = (col < g.N) ? g.bias[col] : 0.f;
#pragma unroll
        for (int mi = 0; mi < F; mi++)
#pragma unroll
            for (int reg = 0; reg < 4; reg++) acc[mi][ni][reg] += bv;
    }
    // fused BN stats (fp32, pre-rounding)
    if (g.stats) {
#pragma unroll
        for (int ni = 0; ni < F; ni++) {
            float s = 0.f, s2 = 0.f;
#pragma unroll
            for (int mi = 0; mi < F; mi++)
#pragma unroll
                for (int reg = 0; reg < 4; reg++) {
                    int row = bm + wm + mi * 16 + rq * 4 + reg;
                    if (row < g.M) { float v = acc[mi][ni][reg]; s += v; s2 += v * v; }
                }
            s  += __shfl_xor(s, 16);  s  += __shfl_xor(s, 32);
            s2 += __shfl_xor(s2, 16); s2 += __shfl_xor(s2, 32);
            if (rq == 0) {
                int col = bn + wn + ni * 16 + ci;
                atomicAdd(&g.stats[col], s);
                atomicAdd(&g.stats[HD + col], s2);
            }
        }
    }
#pragma unroll
    for (int mi = 0; mi < F; mi++)
#pragma unroll
        for (int ni = 0; ni < F; ni++)
#pragma unroll
            for (int reg = 0; reg < 4; reg++) {
                int row = bm + wm + mi * 16 + rq * 4 + reg;
                int col = bn + wn + ni * 16 + ci;
                if (row < g.M && col < g.N) {
                    float v = acc[mi][ni][reg];
                    if (g.Cb) g.Cb[(size_t)row * HD + col] = f2b(v);
                    else      g.Cf[(size_t)row * g.N + col] = v;
                }
            }
}

// ---------------------------------------------------------------------------
extern "C" void kernel_launch(void* const* d_in, const int* in_sizes, int n_in,
                              void* d_out, int out_size, void* d_ws, size_t ws_size,
                              hipStream_t stream) {
    const float* x   = (const float*)d_in[0];
    const int* src0  = (const int*)d_in[1];
    const int* dst0  = (const int*)d_in[2];
    const int* et0   = (const int*)d_in[3];
    const int* src1  = (const int*)d_in[4];
    const int* dst1  = (const int*)d_in[5];
    const int* et1   = (const int*)d_in[6];
    const float* W0  = (const float*)d_in[9];
    const float* Wl0 = (const float*)d_in[10];
    const float* b0  = (const float*)d_in[11];
    const float* g0  = (const float*)d_in[12];
    const float* be0 = (const float*)d_in[13];
    const float* W1  = (const float*)d_in[14];
    const float* Wl1 = (const float*)d_in[15];
    const float* b1  = (const float*)d_in[16];
    const float* g1  = (const float*)d_in[17];
    const float* be1 = (const float*)d_in[18];
    const float* Wm1 = (const float*)d_in[19];
    const float* bm1 = (const float*)d_in[20];
    const float* gm  = (const float*)d_in[21];
    const float* bem = (const float*)d_in[22];
    const float* Wm2 = (const float*)d_in[23];
    const float* bm2 = (const float*)d_in[24];

    const int E0 = in_sizes[1];
    const int E1 = in_sizes[4];
    const int NOUT = in_sizes[24];     // 153
    const int NSRC = in_sizes[0] / HD; // 200000
    const int NBKT = NREL * ND0 + NREL * ND1;  // 300000

    // ---------------- ws layout (~305 MB of ~819 MB) -----------------------
    char* p = (char*)d_ws;
    ushort_t* Wt = (ushort_t*)p;  p += (size_t)14 * 65536 * 2;
    float* st    = (float*)p;     p += 1536 * 4;    // st0 | st1 | stm (512 ea)
    float* bnp   = (float*)p;     p += 6 * 256 * 4; // sc0,sh0,sc1,sh1,scm,shm
    int* cnt     = (int*)p;       p += (size_t)NBKT * 4;
    int* off     = (int*)p;       p += (size_t)NBKT * 4;
    int* bsum    = (int*)p;       p += 1024 * 4;
    int* pos     = (int*)p;       p += (size_t)(E0 + E1) * 4;
    int* ssrc    = (int*)p;       p += (size_t)(E0 + E1) * 4;
    ushort_t* xb  = (ushort_t*)p; p += (size_t)NSRC * HD * 2;
    ushort_t* S0  = (ushort_t*)p; p += (size_t)(NREL * ND0 + 128) * HD * 2;
    ushort_t* S1  = (ushort_t*)p; p += (size_t)(NREL * ND1 + 128) * HD * 2;
    ushort_t* h0b = (ushort_t*)p; p += (size_t)(ND0 + 128) * HD * 2;
    ushort_t* h1b = (ushort_t*)p; p += (size_t)(ND1 + 128) * HD * 2;
    ushort_t* mb  = (ushort_t*)p; p += (size_t)(ND1 + 128) * HD * 2;

    float* st0 = st, *st1 = st + 512, *stm = st + 1024;
    float* sc0 = bnp, *sh0 = bnp + 256, *sc1 = bnp + 512, *sh1 = bnp + 768;
    float* scm = bnp + 1024, *shm = bnp + 1280;

    ushort_t* W0t  = Wt;
    ushort_t* Wl0t = Wt + 5 * 65536;
    ushort_t* W1t  = Wt + 6 * 65536;
    ushort_t* Wl1t = Wt + 11 * 65536;
    ushort_t* Wm1t = Wt + 12 * 65536;
    ushort_t* Wm2t = Wt + 13 * 65536;

    // ---------------- prep: weights, xb, zeroing ---------------------------
    {
        WconvArgs wa;
        for (int r = 0; r < NREL; r++) { wa.src[r] = W0 + (size_t)r * 65536; wa.dst[r] = W0t + (size_t)r * 65536; wa.N[r] = 256; }
        wa.src[5] = Wl0; wa.dst[5] = Wl0t; wa.N[5] = 256;
        for (int r = 0; r < NREL; r++) { wa.src[6 + r] = W1 + (size_t)r * 65536; wa.dst[6 + r] = W1t + (size_t)r * 65536; wa.N[6 + r] = 256; }
        wa.src[11] = Wl1; wa.dst[11] = Wl1t; wa.N[11] = 256;
        wa.src[12] = Wm1; wa.dst[12] = Wm1t; wa.N[12] = 256;
        wa.src[13] = Wm2; wa.dst[13] = Wm2t; wa.N[13] = NOUT;
        wconv_all_kernel<<<14 * 256, 256, 0, stream>>>(wa);
    }
    xconv_kernel<<<(NSRC * 64 + 255) / 256, 256, 0, stream>>>(x, xb, NSRC * 64);
    hipMemsetAsync(st, 0, 1536 * sizeof(float), stream);
    hipMemsetAsync(cnt, 0, (size_t)NBKT * sizeof(int), stream);

    // ---------------- combined CSR (both layers) ---------------------------
    int ET = E0 + E1;
    count2_kernel<<<(ET + 255) / 256, 256, 0, stream>>>(dst0, et0, E0, dst1, et1, E1, cnt, pos);
    int nsb = (NBKT + 1023) / 1024;
    scan_block_kernel<<<nsb, 256, 0, stream>>>(cnt, off, bsum, NBKT);
    scan_block_kernel<<<1, 256, 0, stream>>>(bsum, bsum, nullptr, nsb);
    scan_add_kernel<<<(NBKT + 255) / 256, 256, 0, stream>>>(off, bsum, NBKT);
    fill2_kernel<<<(ET + 255) / 256, 256, 0, stream>>>(src0, dst0, et0, E0, src1, dst1, et1, E1, pos, off, ssrc);

    // ---------------- layer 0: gather + fused GEMM (stats fused) -----------
    gather_kernel<<<(NREL * ND0 * 64) / 256, 256, 0, stream>>>(
        xb, ssrc, cnt, off, NREL * ND0, S0, nullptr, nullptr);
    {
        GemmArgs ga = {};
        for (int s = 0; s < NREL; s++)
            ga.seg[s] = { S0 + (size_t)s * ND0 * HD, W0t + (size_t)s * 65536, nullptr, nullptr, 0 };
        ga.seg[5] = { xb, Wl0t, nullptr, nullptr, 0 };
        ga.nseg = 6; ga.bias = b0; ga.stats = st0;
        ga.Cb = h0b; ga.Cf = nullptr; ga.M = ND0; ga.N = HD;
        gemm_mfma_kernel<128><<<dim3(2, (ND0 + 127) / 128), 256, 0, stream>>>(ga);
    }
    bnprep_kernel<<<1, 256, 0, stream>>>(st0, g0, be0, 1.f / ND0, sc0, sh0);

    // ---------------- layer 1: gather (BN+ELU fused) + fused GEMM ----------
    gather_kernel<<<(NREL * ND1 * 64) / 256, 256, 0, stream>>>(
        h0b, ssrc, cnt + NREL * ND0, off + NREL * ND0, NREL * ND1, S1, sc0, sh0);
    {
        GemmArgs ga = {};
        for (int s = 0; s < NREL; s++)
            ga.seg[s] = { S1 + (size_t)s * ND1 * HD, W1t + (size_t)s * 65536, nullptr, nullptr, 0 };
        ga.seg[5] = { h0b, Wl1t, sc0, sh0, 1 };
        ga.nseg = 6; ga.bias = b1; ga.stats = st1;
        ga.Cb = h1b; ga.Cf = nullptr; ga.M = ND1; ga.N = HD;
        gemm_mfma_kernel<64><<<dim3(4, (ND1 + 63) / 64), 256, 0, stream>>>(ga);
    }
    bnprep_kernel<<<1, 256, 0, stream>>>(st1, g1, be1, 1.f / ND1, sc1, sh1);

    // ---------------- MLP head ---------------------------------------------
    {
        GemmArgs ga = {};
        ga.seg[0] = { h1b, Wm1t, sc1, sh1, 1 };
        ga.nseg = 1; ga.bias = bm1; ga.stats = stm;
        ga.Cb = mb; ga.Cf = nullptr; ga.M = ND1; ga.N = HD;
        gemm_mfma_kernel<64><<<dim3(4, (ND1 + 63) / 64), 256, 0, stream>>>(ga);
    }
    bnprep_kernel<<<1, 256, 0, stream>>>(stm, gm, bem, 1.f / ND1, scm, shm);
    {
        GemmArgs ga = {};
        ga.seg[0] = { mb, Wm2t, scm, shm, 2 };
        ga.nseg = 1; ga.bias = bm2; ga.stats = nullptr;
        ga.Cb = nullptr; ga.Cf = (float*)d_out; ga.M = ND1; ga.N = NOUT;
        gemm_mfma_kernel<64><<<dim3((NOUT + 63) / 64, (ND1 + 63) / 64), 256, 0, stream>>>(ga);
    }
}